// Round 6
// baseline (51.253 us; speedup 1.0000x reference)
//
#include <hip/hip_runtime.h>

#define NB   4
#define CIN  32
#define HH   56
#define WW   56
#define GIN  8
#define GOUT 8
#define LIN  4
#define LOUT 8
#define KK   9
#define HW   (HH * WW)        // 3136
#define PIXTOT (NB * HW)      // 12544
#define PPB  32               // pixels per block (256 thr = 32 pix * 8 g)
#define WSLICE (GIN * KK * LIN * LOUT)  // 2304 floats per c
#define WS_G 292              // padded per-g LDS stride -> conflict-free float4 reads

__global__ __launch_bounds__(256, 2) void caps_routing_kernel(
    const float* __restrict__ x, const float* __restrict__ wt,
    float* __restrict__ out)
{
    __shared__ float ws[GIN * WS_G];   // 9344 B

    const int tid = threadIdx.x;
    const int c = blockIdx.y;

    const int g  = tid & 7;
    const int pl = tid >> 3;
    const int pix = blockIdx.x * PPB + pl;   // 392*32 == 12544 exactly
    const int n = pix / HW;
    const int p = pix - n * HW;
    const int h = p / WW;
    const int w = p - h * WW;

    // ---- issue the x-gather FIRST so its latency overlaps weight staging ----
    float xv[KK][LIN];
    const float* xb = x + (n * CIN + g * LIN) * HW;
    #pragma unroll
    for (int ki = 0; ki < 3; ++ki) {
        const int hh = h - 1 + ki;
        const bool hok = (unsigned)hh < (unsigned)HH;
        #pragma unroll
        for (int kj = 0; kj < 3; ++kj) {
            const int wp = w - 1 + kj;
            const bool ok = hok && ((unsigned)wp < (unsigned)WW);
            const int off = hh * WW + wp;
            #pragma unroll
            for (int l = 0; l < LIN; ++l)
                xv[ki * 3 + kj][l] = ok ? xb[l * HW + off] : 0.0f;
        }
    }

    // ---- stage this c's weight slice: [g][k][l][m], per-g padded to 292 ----
    const float* wsrc = wt + c * WSLICE;
    for (int i = tid; i < WSLICE; i += 256) {
        const int gg = i / 288;
        const int r = i - gg * 288;
        ws[gg * WS_G + r] = wsrc[i];
    }
    __syncthreads();

    // ---- priors[k][m] = sum_l xv[k][l] * W[c,g,k,l,m]; also k-sum for iter0 ----
    float pr[KK][LOUT];
    float ksum[LOUT];
    #pragma unroll
    for (int m = 0; m < LOUT; ++m) ksum[m] = 0.0f;

    const float* wg = &ws[g * WS_G];
    #pragma unroll
    for (int k = 0; k < KK; ++k) {
        float4 a0 = make_float4(0.f, 0.f, 0.f, 0.f);
        float4 a1 = make_float4(0.f, 0.f, 0.f, 0.f);
        #pragma unroll
        for (int l = 0; l < LIN; ++l) {
            const float4* wp4 = reinterpret_cast<const float4*>(wg + k * 32 + l * 8);
            const float xs = xv[k][l];
            const float4 w0 = wp4[0];
            const float4 w1 = wp4[1];
            a0.x = fmaf(xs, w0.x, a0.x); a0.y = fmaf(xs, w0.y, a0.y);
            a0.z = fmaf(xs, w0.z, a0.z); a0.w = fmaf(xs, w0.w, a0.w);
            a1.x = fmaf(xs, w1.x, a1.x); a1.y = fmaf(xs, w1.y, a1.y);
            a1.z = fmaf(xs, w1.z, a1.z); a1.w = fmaf(xs, w1.w, a1.w);
        }
        pr[k][0] = a0.x; pr[k][1] = a0.y; pr[k][2] = a0.z; pr[k][3] = a0.w;
        pr[k][4] = a1.x; pr[k][5] = a1.y; pr[k][6] = a1.z; pr[k][7] = a1.w;
        #pragma unroll
        for (int m = 0; m < LOUT; ++m) ksum[m] += pr[k][m];
    }

    // ---- pin priors in VGPRs: opaque to the optimizer -> no rematerialization
    #pragma unroll
    for (int k = 0; k < KK; ++k)
        #pragma unroll
        for (int m = 0; m < LOUT; ++m)
            asm volatile("" : "+v"(pr[k][m]));

    // ---- dynamic routing, ITERS = 3, fully in registers ----
    float logits[KK];
    #pragma unroll
    for (int k = 0; k < KK; ++k) logits[k] = 0.0f;

    float v[LOUT];
    #pragma unroll
    for (int it = 0; it < 3; ++it) {
        float s[LOUT];
        if (it == 0) {
            // softmax(0) = 1/9 uniform: s-partial is the prior k-sum / 9
            #pragma unroll
            for (int m = 0; m < LOUT; ++m) s[m] = ksum[m] * (1.0f / 9.0f);
        } else {
            float probs[KK];
            float mx = logits[0];
            #pragma unroll
            for (int k = 1; k < KK; ++k) mx = fmaxf(mx, logits[k]);
            float sum = 0.0f;
            #pragma unroll
            for (int k = 0; k < KK; ++k) { probs[k] = __expf(logits[k] - mx); sum += probs[k]; }
            const float inv = 1.0f / sum;
            #pragma unroll
            for (int k = 0; k < KK; ++k) probs[k] *= inv;
            #pragma unroll
            for (int m = 0; m < LOUT; ++m) {
                float acc = 0.0f;
                #pragma unroll
                for (int k = 0; k < KK; ++k) acc = fmaf(probs[k], pr[k][m], acc);
                s[m] = acc;
            }
        }

        // reduce partial s over the 8 g-lanes (in-wave butterfly)
        #pragma unroll
        for (int off = 1; off < 8; off <<= 1) {
            #pragma unroll
            for (int m = 0; m < LOUT; ++m)
                s[m] += __shfl_xor(s[m], off, 64);
        }

        // squash: v = (|s| / (1 + |s|^2)) * s
        float n2 = 0.0f;
        #pragma unroll
        for (int m = 0; m < LOUT; ++m) n2 = fmaf(s[m], s[m], n2);
        const float f = sqrtf(n2) / (1.0f + n2);
        #pragma unroll
        for (int m = 0; m < LOUT; ++m) v[m] = f * s[m];

        if (it != 2) {
            #pragma unroll
            for (int k = 0; k < KK; ++k) {
                float d = 0.0f;
                #pragma unroll
                for (int m = 0; m < LOUT; ++m) d = fmaf(pr[k][m], v[m], d);
                logits[k] += d;
            }
        }
    }

    // lane (pl, g) writes output component m = g
    float outv = v[0];
    #pragma unroll
    for (int m = 1; m < LOUT; ++m) if (g == m) outv = v[m];
    out[(n * GOUT * LOUT + c * LOUT + g) * HW + p] = outv;
}

extern "C" void kernel_launch(void* const* d_in, const int* in_sizes, int n_in,
                              void* d_out, int out_size, void* d_ws, size_t ws_size,
                              hipStream_t stream) {
    const float* x  = (const float*)d_in[0];
    const float* wt = (const float*)d_in[1];
    float* out = (float*)d_out;
    dim3 grid(PIXTOT / PPB, GOUT);   // 392 x 8
    caps_routing_kernel<<<grid, dim3(256), 0, stream>>>(x, wt, out);
}

// Round 7
// 38.487 us; speedup vs baseline: 1.3317x; 1.3317x over previous
//
#include <hip/hip_runtime.h>

#define NB   4
#define CIN  32
#define HH   56
#define WW   56
#define GIN  8
#define GOUT 8
#define LIN  4
#define LOUT 8
#define KK   9
#define HW   (HH * WW)        // 3136
#define PIXTOT (NB * HW)      // 12544
#define PPB  32               // pixels per block (256 thr = 32 pix * 8 g)
#define WSLICE (GIN * KK * LIN * LOUT)  // 2304 floats per c
#define WS_G 292              // padded per-g LDS stride -> conflict-free float4 reads

// ---- pre-pass: x[n][ch][h][w] -> xt[n][h][w][ch]  (enables float4 patch loads)
__global__ __launch_bounds__(256) void transpose_x_kernel(
    const float* __restrict__ x, float* __restrict__ xt)
{
    __shared__ float tile[CIN * 57];     // 57 stride: conflict-free transposed read
    const int b = blockIdx.x;            // n*HH + h
    const int n = b / HH;
    const int h = b - n * HH;
    const int tid = threadIdx.x;
    for (int i = tid; i < CIN * WW; i += 256) {
        const int ch = i / WW;
        const int w  = i - ch * WW;      // lanes: w consecutive -> coalesced read
        tile[ch * 57 + w] = x[((n * CIN + ch) * HH + h) * WW + w];
    }
    __syncthreads();
    for (int i = tid; i < WW * CIN; i += 256) {
        const int w  = i >> 5;
        const int ch = i & 31;           // lanes: ch consecutive -> coalesced write
        xt[((n * HH + h) * WW + w) * CIN + ch] = tile[ch * 57 + w];
    }
}

__global__ __launch_bounds__(256) void caps_routing_kernel(
    const float* __restrict__ xt, const float* __restrict__ wt,
    float* __restrict__ out)
{
    __shared__ float ws[GIN * WS_G];   // 9344 B

    const int tid = threadIdx.x;
    const int c = blockIdx.y;

    const int g  = tid & 7;
    const int pl = tid >> 3;
    const int pix = blockIdx.x * PPB + pl;   // 392*32 == 12544 exactly
    const int n = pix / HW;
    const int p = pix - n * HW;
    const int h = p / WW;
    const int w = p - h * WW;

    // ---- x-gather first (overlaps weight staging): 9 float4 loads from xt ----
    float4 xv4[KK];
    const float* xtn = xt + (n * HW) * CIN + g * 4;
    if (h >= 1 && h <= HH - 2 && w >= 1 && w <= WW - 2) {
        // interior fast path (93% of threads): no predication at all
        const float* base = xtn + ((h - 1) * WW + (w - 1)) * CIN;
        #pragma unroll
        for (int ki = 0; ki < 3; ++ki)
            #pragma unroll
            for (int kj = 0; kj < 3; ++kj)
                xv4[ki * 3 + kj] =
                    *reinterpret_cast<const float4*>(base + (ki * WW + kj) * CIN);
    } else {
        #pragma unroll
        for (int ki = 0; ki < 3; ++ki) {
            const int hh = h - 1 + ki;
            const bool hok = (unsigned)hh < (unsigned)HH;
            #pragma unroll
            for (int kj = 0; kj < 3; ++kj) {
                const int wp = w - 1 + kj;
                const bool ok = hok && ((unsigned)wp < (unsigned)WW);
                xv4[ki * 3 + kj] = ok
                    ? *reinterpret_cast<const float4*>(xtn + (hh * WW + wp) * CIN)
                    : make_float4(0.f, 0.f, 0.f, 0.f);
            }
        }
    }

    // ---- stage this c's weight slice: [g][k][l][m], per-g padded to 292 ----
    const float* wsrc = wt + c * WSLICE;
    for (int i = tid; i < WSLICE; i += 256) {
        const int gg = i / 288;
        const int r = i - gg * 288;
        ws[gg * WS_G + r] = wsrc[i];
    }
    __syncthreads();

    // ---- priors[k][m] = sum_l xv[k][l] * W[c,g,k,l,m]; k-sum fused for iter0 ----
    float pr[KK][LOUT];
    float ksum[LOUT];
    #pragma unroll
    for (int m = 0; m < LOUT; ++m) ksum[m] = 0.0f;

    const float* wg = &ws[g * WS_G];
    #pragma unroll
    for (int k = 0; k < KK; ++k) {
        float4 a0 = make_float4(0.f, 0.f, 0.f, 0.f);
        float4 a1 = make_float4(0.f, 0.f, 0.f, 0.f);
        const float xl[4] = { xv4[k].x, xv4[k].y, xv4[k].z, xv4[k].w };
        #pragma unroll
        for (int l = 0; l < LIN; ++l) {
            const float4* wp4 = reinterpret_cast<const float4*>(wg + k * 32 + l * 8);
            const float xs = xl[l];
            const float4 w0 = wp4[0];
            const float4 w1 = wp4[1];
            a0.x = fmaf(xs, w0.x, a0.x); a0.y = fmaf(xs, w0.y, a0.y);
            a0.z = fmaf(xs, w0.z, a0.z); a0.w = fmaf(xs, w0.w, a0.w);
            a1.x = fmaf(xs, w1.x, a1.x); a1.y = fmaf(xs, w1.y, a1.y);
            a1.z = fmaf(xs, w1.z, a1.z); a1.w = fmaf(xs, w1.w, a1.w);
        }
        pr[k][0] = a0.x; pr[k][1] = a0.y; pr[k][2] = a0.z; pr[k][3] = a0.w;
        pr[k][4] = a1.x; pr[k][5] = a1.y; pr[k][6] = a1.z; pr[k][7] = a1.w;
        #pragma unroll
        for (int m = 0; m < LOUT; ++m) ksum[m] += pr[k][m];
    }

    // ---- dynamic routing, ITERS = 3 ----
    float logits[KK];
    #pragma unroll
    for (int k = 0; k < KK; ++k) logits[k] = 0.0f;

    float v[LOUT];
    #pragma unroll
    for (int it = 0; it < 3; ++it) {
        float s[LOUT];
        if (it == 0) {
            #pragma unroll
            for (int m = 0; m < LOUT; ++m) s[m] = ksum[m] * (1.0f / 9.0f);
        } else {
            float probs[KK];
            float mx = logits[0];
            #pragma unroll
            for (int k = 1; k < KK; ++k) mx = fmaxf(mx, logits[k]);
            float sum = 0.0f;
            #pragma unroll
            for (int k = 0; k < KK; ++k) { probs[k] = __expf(logits[k] - mx); sum += probs[k]; }
            const float inv = 1.0f / sum;
            #pragma unroll
            for (int k = 0; k < KK; ++k) probs[k] *= inv;
            #pragma unroll
            for (int m = 0; m < LOUT; ++m) {
                float acc = 0.0f;
                #pragma unroll
                for (int k = 0; k < KK; ++k) acc = fmaf(probs[k], pr[k][m], acc);
                s[m] = acc;
            }
        }

        // reduce partial s over the 8 g-lanes (in-wave butterfly)
        #pragma unroll
        for (int off = 1; off < 8; off <<= 1) {
            #pragma unroll
            for (int m = 0; m < LOUT; ++m)
                s[m] += __shfl_xor(s[m], off, 64);
        }

        // squash: v = (|s| / (1 + |s|^2)) * s
        float n2 = 0.0f;
        #pragma unroll
        for (int m = 0; m < LOUT; ++m) n2 = fmaf(s[m], s[m], n2);
        const float f = sqrtf(n2) / (1.0f + n2);
        #pragma unroll
        for (int m = 0; m < LOUT; ++m) v[m] = f * s[m];

        if (it != 2) {
            #pragma unroll
            for (int k = 0; k < KK; ++k) {
                float d = 0.0f;
                #pragma unroll
                for (int m = 0; m < LOUT; ++m) d = fmaf(pr[k][m], v[m], d);
                logits[k] += d;
            }
        }
    }

    // lane (pl, g) writes output component m = g
    float outv = v[0];
    #pragma unroll
    for (int m = 1; m < LOUT; ++m) if (g == m) outv = v[m];
    out[(n * GOUT * LOUT + c * LOUT + g) * HW + p] = outv;
}

extern "C" void kernel_launch(void* const* d_in, const int* in_sizes, int n_in,
                              void* d_out, int out_size, void* d_ws, size_t ws_size,
                              hipStream_t stream) {
    const float* x  = (const float*)d_in[0];
    const float* wt = (const float*)d_in[1];
    float* out = (float*)d_out;
    float* xt = (float*)d_ws;   // 12544*32 floats = 1.6 MB scratch

    transpose_x_kernel<<<dim3(NB * HH), dim3(256), 0, stream>>>(x, xt);
    dim3 grid(PIXTOT / PPB, GOUT);   // 392 x 8
    caps_routing_kernel<<<grid, dim3(256), 0, stream>>>(xt, wt, out);
}

// Round 8
// 34.288 us; speedup vs baseline: 1.4948x; 1.1224x over previous
//
#include <hip/hip_runtime.h>

#define NB   4
#define CIN  32
#define HH   56
#define WW   56
#define GIN  8
#define GOUT 8
#define LIN  4
#define LOUT 8
#define KK   9
#define HW   (HH * WW)        // 3136
#define PIXTOT (NB * HW)      // 12544
#define PPB  32               // pixels per block (256 thr = 32 pix * 8 g)
#define WSLICE (GIN * KK * LIN * LOUT)  // 2304 floats per c
#define WS_G 292              // padded per-g LDS stride -> conflict-free float4 reads
#define HP   58               // padded spatial dim
#define WP   58

typedef float v2f __attribute__((ext_vector_type(2)));
typedef float v4f __attribute__((ext_vector_type(4)));

static __device__ __forceinline__ v2f fma2(v2f a, v2f b, v2f c) {
    return __builtin_elementwise_fma(a, b, c);
}

// ---- pre-pass: x[n][ch][h][w] -> xt[n][hp][wp][ch] with zero border ----
__global__ __launch_bounds__(256) void transpose_x_kernel(
    const float* __restrict__ x, float* __restrict__ xt)
{
    __shared__ float tile[CIN * 57];     // 57 stride: conflict-free transposed read
    const int b = blockIdx.x;            // n*HP + hp
    const int n = b / HP;
    const int hp = b - n * HP;
    const int h = hp - 1;
    const int tid = threadIdx.x;
    const bool rowok = (unsigned)h < (unsigned)HH;

    if (rowok) {
        for (int i = tid; i < CIN * WW; i += 256) {
            const int ch = i / WW;
            const int w  = i - ch * WW;  // lanes: w consecutive -> coalesced read
            tile[ch * 57 + w] = x[((n * CIN + ch) * HH + h) * WW + w];
        }
    }
    __syncthreads();
    float* dst = xt + ((size_t)(n * HP + hp) * WP) * CIN;
    for (int i = tid; i < WP * CIN; i += 256) {
        const int wp = i >> 5;
        const int ch = i & 31;           // lanes: ch consecutive -> coalesced write
        const bool ok = rowok && (wp >= 1) && (wp <= WW);
        dst[i] = ok ? tile[ch * 57 + (wp - 1)] : 0.0f;
    }
}

__global__ __launch_bounds__(256) void caps_routing_kernel(
    const float* __restrict__ xt, const float* __restrict__ wt,
    float* __restrict__ out)
{
    __shared__ __align__(16) float ws[GIN * WS_G];   // 9344 B

    const int tid = threadIdx.x;
    const int c = blockIdx.y;

    const int g  = tid & 7;
    const int pl = tid >> 3;
    const int pix = blockIdx.x * PPB + pl;   // 392*32 == 12544 exactly
    const int n = pix / HW;
    const int p = pix - n * HW;
    const int h = p / WW;
    const int w = p - h * WW;

    // ---- x-gather: 9 unconditional float4 loads from the padded layout ----
    v4f xv4[KK];
    const float* base = xt + ((size_t)((n * HP + h) * WP + w)) * CIN + g * 4;
    #pragma unroll
    for (int ki = 0; ki < 3; ++ki)
        #pragma unroll
        for (int kj = 0; kj < 3; ++kj)
            xv4[ki * 3 + kj] =
                *reinterpret_cast<const v4f*>(base + (ki * WP + kj) * CIN);

    // ---- stage this c's weight slice: [g][k][l][m], per-g padded to 292 ----
    // thread t: group gg = t>>5; 32 threads stage 288 floats (9 each), no divisions
    {
        const int gg = tid >> 5;
        const int r0 = tid & 31;
        const float* src = wt + c * WSLICE + gg * 288;
        float* dst = ws + gg * WS_G;
        #pragma unroll
        for (int j = 0; j < 9; ++j)
            dst[r0 + j * 32] = src[r0 + j * 32];
    }
    __syncthreads();

    // ---- priors (packed pairs): pr2[k][j] = m-pair j of prior vector k ----
    v2f pr2[KK][4];
    v2f ks2[4] = {v2f{0.f,0.f}, v2f{0.f,0.f}, v2f{0.f,0.f}, v2f{0.f,0.f}};

    const float* wg = &ws[g * WS_G];
    #pragma unroll
    for (int k = 0; k < KK; ++k) {
        v2f a0 = {0.f,0.f}, a1 = {0.f,0.f}, a2 = {0.f,0.f}, a3 = {0.f,0.f};
        #pragma unroll
        for (int l = 0; l < LIN; ++l) {
            const float xs = xv4[k][l];
            const v2f xs2 = {xs, xs};
            const v4f w01 = *reinterpret_cast<const v4f*>(wg + k * 32 + l * 8);
            const v4f w23 = *reinterpret_cast<const v4f*>(wg + k * 32 + l * 8 + 4);
            a0 = fma2(xs2, __builtin_shufflevector(w01, w01, 0, 1), a0);
            a1 = fma2(xs2, __builtin_shufflevector(w01, w01, 2, 3), a1);
            a2 = fma2(xs2, __builtin_shufflevector(w23, w23, 0, 1), a2);
            a3 = fma2(xs2, __builtin_shufflevector(w23, w23, 2, 3), a3);
        }
        pr2[k][0] = a0; pr2[k][1] = a1; pr2[k][2] = a2; pr2[k][3] = a3;
        ks2[0] += a0; ks2[1] += a1; ks2[2] += a2; ks2[3] += a3;
    }

    // ---- dynamic routing, ITERS = 3 ----
    float logits[KK];
    #pragma unroll
    for (int k = 0; k < KK; ++k) logits[k] = 0.0f;

    v2f v2[4];
    #pragma unroll
    for (int it = 0; it < 3; ++it) {
        v2f s2[4];
        if (it == 0) {
            #pragma unroll
            for (int j = 0; j < 4; ++j) s2[j] = ks2[j] * (1.0f / 9.0f);
        } else {
            // softmax without max-subtraction (|logits| small); 1/sum folded in
            float e[KK];
            float sum = 0.0f;
            #pragma unroll
            for (int k = 0; k < KK; ++k) { e[k] = __expf(logits[k]); sum += e[k]; }
            const float inv = 1.0f / sum;
            #pragma unroll
            for (int j = 0; j < 4; ++j) s2[j] = v2f{0.f, 0.f};
            #pragma unroll
            for (int k = 0; k < KK; ++k) {
                const v2f ek = {e[k], e[k]};
                #pragma unroll
                for (int j = 0; j < 4; ++j) s2[j] = fma2(ek, pr2[k][j], s2[j]);
            }
            const v2f inv2 = {inv, inv};
            #pragma unroll
            for (int j = 0; j < 4; ++j) s2[j] *= inv2;
        }

        // reduce partial s over the 8 g-lanes (in-wave butterfly)
        #pragma unroll
        for (int off = 1; off < 8; off <<= 1) {
            #pragma unroll
            for (int j = 0; j < 4; ++j) {
                s2[j].x += __shfl_xor(s2[j].x, off, 64);
                s2[j].y += __shfl_xor(s2[j].y, off, 64);
            }
        }

        // squash: v = (|s| / (1 + |s|^2)) * s
        v2f t = s2[0] * s2[0];
        t = fma2(s2[1], s2[1], t);
        t = fma2(s2[2], s2[2], t);
        t = fma2(s2[3], s2[3], t);
        const float n2 = t.x + t.y;
        const float f = sqrtf(n2) / (1.0f + n2);
        const v2f f2 = {f, f};
        #pragma unroll
        for (int j = 0; j < 4; ++j) v2[j] = f2 * s2[j];

        if (it != 2) {
            #pragma unroll
            for (int k = 0; k < KK; ++k) {
                v2f d2 = pr2[k][0] * v2[0];
                d2 = fma2(pr2[k][1], v2[1], d2);
                d2 = fma2(pr2[k][2], v2[2], d2);
                d2 = fma2(pr2[k][3], v2[3], d2);
                logits[k] += d2.x + d2.y;
            }
        }
    }

    // lane (pl, g) writes output component m = g (static select chain)
    const float vs[8] = { v2[0].x, v2[0].y, v2[1].x, v2[1].y,
                          v2[2].x, v2[2].y, v2[3].x, v2[3].y };
    float outv = vs[0];
    #pragma unroll
    for (int m = 1; m < LOUT; ++m) if (g == m) outv = vs[m];
    out[(n * GOUT * LOUT + c * LOUT + g) * HW + p] = outv;
}

extern "C" void kernel_launch(void* const* d_in, const int* in_sizes, int n_in,
                              void* d_out, int out_size, void* d_ws, size_t ws_size,
                              hipStream_t stream) {
    const float* x  = (const float*)d_in[0];
    const float* wt = (const float*)d_in[1];
    float* out = (float*)d_out;
    float* xt = (float*)d_ws;   // 4*58*58*32 floats = 1.72 MB scratch

    transpose_x_kernel<<<dim3(NB * HP), dim3(256), 0, stream>>>(x, xt);
    dim3 grid(PIXTOT / PPB, GOUT);   // 392 x 8
    caps_routing_kernel<<<grid, dim3(256), 0, stream>>>(xt, wt, out);
}